// Round 4
// baseline (223.502 us; speedup 1.0000x reference)
//
#include <hip/hip_runtime.h>
#include <stdint.h>

// Problem constants: B=4, N=8192, G=512, E=512, D=3E=1536
#define NB 4
#define NP 8192
#define NG 512
#define DF 1536
#define NC 512

using f32x4   = __attribute__((ext_vector_type(4))) float;
using bf16x8  = __attribute__((ext_vector_type(8))) __bf16;
using ushort8v = __attribute__((ext_vector_type(8))) unsigned short;

__device__ __forceinline__ unsigned short f32_to_bf16(float f) {
  unsigned int u = __float_as_uint(f);
  u += 0x7fffu + ((u >> 16) & 1u);   // round-to-nearest-even
  return (unsigned short)(u >> 16);
}

// ---------------- prep: BN fold + w1/w2 casts, one kernel -------------------
__global__ __launch_bounds__(256) void prep_kernel(
    const float* __restrict__ w1, const float* __restrict__ w2,
    const float* __restrict__ g1, const float* __restrict__ be1,
    const float* __restrict__ m1, const float* __restrict__ v1,
    const float* __restrict__ g2, const float* __restrict__ be2,
    const float* __restrict__ m2, const float* __restrict__ v2,
    unsigned short* __restrict__ w1b, unsigned short* __restrict__ w2b,
    float* __restrict__ s1, float* __restrict__ t1,
    float* __restrict__ s2, float* __restrict__ t2)
{
  const int t = blockIdx.x * 256 + threadIdx.x;
  if (t < 196608) {                       // w1: 512*1536/4 quads
    float4 v = *(const float4*)&w1[(size_t)t * 4];
    ushort4 o;
    o.x = f32_to_bf16(v.x); o.y = f32_to_bf16(v.y);
    o.z = f32_to_bf16(v.z); o.w = f32_to_bf16(v.w);
    *(ushort4*)&w1b[(size_t)t * 4] = o;
  } else if (t < 262144) {                // w2: 512*512/4 quads
    const int q = t - 196608;
    float4 v = *(const float4*)&w2[(size_t)q * 4];
    ushort4 o;
    o.x = f32_to_bf16(v.x); o.y = f32_to_bf16(v.y);
    o.z = f32_to_bf16(v.z); o.w = f32_to_bf16(v.w);
    *(ushort4*)&w2b[(size_t)q * 4] = o;
  } else if (t < 262272) {                // scales: 128 quads x 4
    const int q = t - 262144;
#pragma unroll
    for (int j = 0; j < 4; ++j) {
      int i = q * 4 + j;
      float sa = g1[i] / sqrtf(v1[i] + 1e-5f);
      s1[i] = sa; t1[i] = be1[i] - m1[i] * sa;
      float sb = g2[i] / sqrtf(v2[i] + 1e-5f);
      s2[i] = sb; t2[i] = be2[i] - m2[i] * sb;
    }
  }
}

// ---------------- cast fused=concat(H4,H8,H12) [2048,1536] f32->bf16 --------
__global__ __launch_bounds__(256) void cast_fused_kernel(
    const float* __restrict__ H4, const float* __restrict__ H8,
    const float* __restrict__ H12, unsigned short* __restrict__ outp)
{
  const int t = blockIdx.x * 256 + threadIdx.x;   // < 2048*384
  const int row = t / 384;
  const int c4 = (t - row * 384) * 4;             // 0..1532
  const float* src = (c4 < 512) ? H4 : (c4 < 1024 ? H8 : H12);
  float4 v = *(const float4*)&src[(size_t)row * 512 + (c4 & 511)];
  ushort4 o;
  o.x = f32_to_bf16(v.x); o.y = f32_to_bf16(v.y);
  o.z = f32_to_bf16(v.z); o.w = f32_to_bf16(v.w);
  *(ushort4*)&outp[(size_t)row * 1536 + c4] = o;
}

// ---------------- KNN: 4 lanes per point, branchless top-3, shfl merge ------
__global__ __launch_bounds__(256) void knn_kernel(
    const float* __restrict__ xyz, const float* __restrict__ centers,
    int* __restrict__ oidx, float* __restrict__ ow)
{
  __shared__ float4 cs[4 * 129];
  const int b = blockIdx.y;
  for (int i = threadIdx.x; i < NG; i += 256) {
    float c0 = centers[((size_t)b * NG + i) * 3 + 0];
    float c1 = centers[((size_t)b * NG + i) * 3 + 1];
    float c2 = centers[((size_t)b * NG + i) * 3 + 2];
    float4 v; v.x = c0; v.y = c1; v.z = c2; v.w = c0 * c0 + c1 * c1 + c2 * c2;
    cs[(i >> 7) * 129 + (i & 127)] = v;
  }
  __syncthreads();
  const int t = blockIdx.x * 256 + threadIdx.x;
  const int p = t >> 2;
  const int q = t & 3;
  const size_t pi = (size_t)b * NP + p;
  const float x0 = xyz[pi * 3 + 0], x1 = xyz[pi * 3 + 1], x2 = xyz[pi * 3 + 2];
  const float xx = x0 * x0 + x1 * x1 + x2 * x2;

  float d0 = 3.4e38f, d1 = 3.4e38f, d2 = 3.4e38f;
  int i0 = 0, i1 = 0, i2 = 0;
  const int gbase = q * 128;
  const float4* csq = cs + q * 129;
#pragma unroll 4
  for (int j = 0; j < 128; ++j) {
    float4 c = csq[j];
    float d = xx + c.w - 2.0f * (x0 * c.x + x1 * c.y + x2 * c.z);
    int g = gbase + j;
    bool c0 = d < d0, c1 = d < d1, c2 = d < d2;
    float nd2 = c1 ? d1 : (c2 ? d : d2); int ni2 = c1 ? i1 : (c2 ? g : i2);
    float nd1 = c0 ? d0 : (c1 ? d : d1); int ni1 = c0 ? i0 : (c1 ? g : i1);
    d0 = c0 ? d : d0;                    i0 = c0 ? g : i0;
    d1 = nd1; i1 = ni1; d2 = nd2; i2 = ni2;
  }
#pragma unroll
  for (int off = 1; off <= 2; off <<= 1) {
    float e0 = __shfl_xor(d0, off), e1 = __shfl_xor(d1, off), e2 = __shfl_xor(d2, off);
    int j0 = __shfl_xor(i0, off), j1 = __shfl_xor(i1, off), j2 = __shfl_xor(i2, off);
#pragma unroll
    for (int s = 0; s < 3; ++s) {
      float e = (s == 0) ? e0 : (s == 1 ? e1 : e2);
      int   j = (s == 0) ? j0 : (s == 1 ? j1 : j2);
      bool c0 = (e < d0) || (e == d0 && j < i0);
      bool c1 = (e < d1) || (e == d1 && j < i1);
      bool c2 = (e < d2) || (e == d2 && j < i2);
      float nd2 = c1 ? d1 : (c2 ? e : d2); int ni2 = c1 ? i1 : (c2 ? j : i2);
      float nd1 = c0 ? d0 : (c1 ? e : d1); int ni1 = c0 ? i0 : (c1 ? j : i1);
      d0 = c0 ? e : d0;                    i0 = c0 ? j : i0;
      d1 = nd1; i1 = ni1; d2 = nd2; i2 = ni2;
    }
  }
  if (q == 0) {
    float r0 = 1.0f / (d0 + 1e-8f), r1 = 1.0f / (d1 + 1e-8f), r2 = 1.0f / (d2 + 1e-8f);
    float inv = 1.0f / (r0 + r1 + r2);
    ow[pi * 3 + 0] = r0 * inv; ow[pi * 3 + 1] = r1 * inv; ow[pi * 3 + 2] = r2 * inv;
    oidx[pi * 3 + 0] = i0; oidx[pi * 3 + 1] = i1; oidx[pi * 3 + 2] = i2;
  }
}

// ---------------- GEMM1: fusedW+BN1 fold, barrier-free wave-split-K ---------
// A=fusedb [2048,1536], Bw=w1b [512,1536]. 64x64 tile/block, 256 blocks.
// Each wave computes full 64x64 over its K-quarter (384) with DIRECT global
// fragment loads (no LDS, no barriers in loop); 4-way LDS reduce at end.
__global__ __launch_bounds__(256) void gemm1_kernel(
    const unsigned short* __restrict__ A, const unsigned short* __restrict__ Bw,
    float* __restrict__ Amat,
    const float* __restrict__ svec, const float* __restrict__ bvec,
    const float* __restrict__ tvec)
{
  __shared__ float red[64 * 65];        // pad 65: lane-quads hit distinct banks
  const int tid = threadIdx.x, lane = tid & 63, wv = tid >> 6;
  const int m0 = (blockIdx.x >> 3) * 64;
  const int n0 = (blockIdx.x & 7) * 64;
  const int ks = wv * 384;

  const unsigned short* Ap = A  + (size_t)(m0 + (lane & 15)) * DF + ks + ((lane >> 4) * 8);
  const unsigned short* Bp = Bw + (size_t)(n0 + (lane & 15)) * DF + ks + ((lane >> 4) * 8);

  f32x4 acc[4][4];
#pragma unroll
  for (int i = 0; i < 4; ++i)
#pragma unroll
    for (int j = 0; j < 4; ++j) acc[i][j] = (f32x4){0.f, 0.f, 0.f, 0.f};

  bf16x8 af[4], bfr[4], afn[4], bfn[4];
#pragma unroll
  for (int i = 0; i < 4; ++i) {
    af[i]  = __builtin_bit_cast(bf16x8, *(const ushort8v*)(Ap + (size_t)i * 16 * DF));
    bfr[i] = __builtin_bit_cast(bf16x8, *(const ushort8v*)(Bp + (size_t)i * 16 * DF));
  }
  for (int k0 = 0;;) {
    const bool more = (k0 + 32 < 384);
    if (more) {
#pragma unroll
      for (int i = 0; i < 4; ++i) {
        afn[i] = __builtin_bit_cast(bf16x8, *(const ushort8v*)(Ap + (size_t)i * 16 * DF + k0 + 32));
        bfn[i] = __builtin_bit_cast(bf16x8, *(const ushort8v*)(Bp + (size_t)i * 16 * DF + k0 + 32));
      }
    }
#pragma unroll
    for (int mi = 0; mi < 4; ++mi)
#pragma unroll
      for (int ni = 0; ni < 4; ++ni)
        acc[mi][ni] = __builtin_amdgcn_mfma_f32_16x16x32_bf16(af[mi], bfr[ni], acc[mi][ni], 0, 0, 0);
    k0 += 32;
    if (!more) break;
#pragma unroll
    for (int i = 0; i < 4; ++i) { af[i] = afn[i]; bfr[i] = bfn[i]; }
  }

  // 4-way cross-wave reduce through LDS (serialized adds, 4 barriers)
  for (int w = 0; w < 4; ++w) {
    if (wv == w) {
#pragma unroll
      for (int mi = 0; mi < 4; ++mi)
#pragma unroll
        for (int ni = 0; ni < 4; ++ni) {
          int col = ni * 16 + (lane & 15);
#pragma unroll
          for (int r = 0; r < 4; ++r) {
            int row = mi * 16 + (lane >> 4) * 4 + r;
            if (w == 0) red[row * 65 + col] = acc[mi][ni][r];
            else        red[row * 65 + col] += acc[mi][ni][r];
          }
        }
    }
    __syncthreads();
  }
  // epilogue: affine, float4 stores (relu deferred to interp)
#pragma unroll
  for (int i = 0; i < 4; ++i) {
    int row = (tid >> 4) + i * 16;
    int col = (tid & 15) * 4;
    float4 v = *(const float4*)&red[row * 65 + col];
    int n = n0 + col;
    v.x = svec[n + 0] * (v.x + bvec[n + 0]) + tvec[n + 0];
    v.y = svec[n + 1] * (v.y + bvec[n + 1]) + tvec[n + 1];
    v.z = svec[n + 2] * (v.z + bvec[n + 2]) + tvec[n + 2];
    v.w = svec[n + 3] * (v.w + bvec[n + 3]) + tvec[n + 3];
    *(float4*)&Amat[(size_t)(m0 + row) * 512 + n] = v;
  }
}

// ---------------- GEMM2: out=relu(s*(h1.w2^T+b)+t), barrier-free direct-load
// A [M,K] bf16, Bw [N,K] bf16. 128x128 tile, 4 waves 2x2, NO LDS: per-lane
// global loads land directly in MFMA fragment layout (16 rows x 64B lines per
// load, fully coalesced at 64B granule). 1-deep register prefetch; compiler
// emits fine-grained vmcnt (no barrier to drain).
__global__ __launch_bounds__(256) void gemm2_kernel(
    const unsigned short* __restrict__ A, const unsigned short* __restrict__ Bw,
    float* __restrict__ outp,
    const float* __restrict__ svec, const float* __restrict__ bvec,
    const float* __restrict__ tvec, int M, int N, int K, int ntiles)
{
  const int tid = threadIdx.x, lane = tid & 63, wv = tid >> 6;
  const int wm = wv >> 1, wn = wv & 1;
  // XCD-aware swizzle: xcd owns contiguous M range -> A-tile L2 reuse
  const int L = blockIdx.x;
  const int xcd = L & 7, slot = L >> 3;
  const int mtper = (M >> 7) >> 3;
  const int mloc = slot / ntiles, nt = slot - mloc * ntiles;
  const int m0 = (xcd * mtper + mloc) * 128, n0 = nt * 128;

  const unsigned short* Ap = A  + (size_t)(m0 + wm * 64 + (lane & 15)) * K + ((lane >> 4) * 8);
  const unsigned short* Bp = Bw + (size_t)(n0 + wn * 64 + (lane & 15)) * K + ((lane >> 4) * 8);

  f32x4 acc[4][4];
#pragma unroll
  for (int i = 0; i < 4; ++i)
#pragma unroll
    for (int j = 0; j < 4; ++j) acc[i][j] = (f32x4){0.f, 0.f, 0.f, 0.f};

  bf16x8 af[4], bfr[4], afn[4], bfn[4];
#pragma unroll
  for (int i = 0; i < 4; ++i) {
    af[i]  = __builtin_bit_cast(bf16x8, *(const ushort8v*)(Ap + (size_t)i * 16 * K));
    bfr[i] = __builtin_bit_cast(bf16x8, *(const ushort8v*)(Bp + (size_t)i * 16 * K));
  }
  for (int k0 = 0;;) {
    const bool more = (k0 + 32 < K);
    if (more) {
#pragma unroll
      for (int i = 0; i < 4; ++i) {
        afn[i] = __builtin_bit_cast(bf16x8, *(const ushort8v*)(Ap + (size_t)i * 16 * K + k0 + 32));
        bfn[i] = __builtin_bit_cast(bf16x8, *(const ushort8v*)(Bp + (size_t)i * 16 * K + k0 + 32));
      }
    }
#pragma unroll
    for (int mi = 0; mi < 4; ++mi)
#pragma unroll
      for (int ni = 0; ni < 4; ++ni)
        acc[mi][ni] = __builtin_amdgcn_mfma_f32_16x16x32_bf16(af[mi], bfr[ni], acc[mi][ni], 0, 0, 0);
    k0 += 32;
    if (!more) break;
#pragma unroll
    for (int i = 0; i < 4; ++i) { af[i] = afn[i]; bfr[i] = bfn[i]; }
  }

  // C/D layout: n = lane&15, m = (lane>>4)*4 + reg   [m89-verified]
#pragma unroll
  for (int mi = 0; mi < 4; ++mi) {
    int mbase = m0 + wm * 64 + mi * 16 + (lane >> 4) * 4;
#pragma unroll
    for (int ni = 0; ni < 4; ++ni) {
      int n = n0 + wn * 64 + ni * 16 + (lane & 15);
      float s = svec[n], bb = bvec[n], t = tvec[n];
      f32x4 v = acc[mi][ni];
#pragma unroll
      for (int r = 0; r < 4; ++r) {
        float val = fmaxf(s * (v[r] + bb) + t, 0.f);
        outp[(size_t)(mbase + r) * N + n] = val;
      }
    }
  }
}

// ---------------- gather + interp + ReLU -> h1 bf16 [32768,512] -------------
__global__ __launch_bounds__(256) void interp_kernel(
    const float* __restrict__ Amat, const int* __restrict__ nidx,
    const float* __restrict__ nw, unsigned short* __restrict__ h1)
{
  const int psub = threadIdx.x >> 7;       // 0..1
  const int c4   = threadIdx.x & 127;      // float4 index
#pragma unroll
  for (int q = 0; q < 4; ++q) {
    const int pp = blockIdx.x * 8 + q * 2 + psub;
    const int b = pp >> 13;                // / 8192
    const int i0 = nidx[pp * 3 + 0], i1 = nidx[pp * 3 + 1], i2 = nidx[pp * 3 + 2];
    const float w0 = nw[pp * 3 + 0], w1v = nw[pp * 3 + 1], w2v = nw[pp * 3 + 2];
    const float4 a0 = *(const float4*)&Amat[((size_t)(b * 512 + i0)) * 512 + c4 * 4];
    const float4 a1 = *(const float4*)&Amat[((size_t)(b * 512 + i1)) * 512 + c4 * 4];
    const float4 a2 = *(const float4*)&Amat[((size_t)(b * 512 + i2)) * 512 + c4 * 4];
    ushort4 o;
    o.x = f32_to_bf16(fmaxf(w0 * a0.x + w1v * a1.x + w2v * a2.x, 0.f));
    o.y = f32_to_bf16(fmaxf(w0 * a0.y + w1v * a1.y + w2v * a2.y, 0.f));
    o.z = f32_to_bf16(fmaxf(w0 * a0.z + w1v * a1.z + w2v * a2.z, 0.f));
    o.w = f32_to_bf16(fmaxf(w0 * a0.w + w1v * a1.w + w2v * a2.w, 0.f));
    *(ushort4*)&h1[(size_t)pp * 512 + c4 * 4] = o;
  }
}

extern "C" void kernel_launch(void* const* d_in, const int* in_sizes, int n_in,
                              void* d_out, int out_size, void* d_ws, size_t ws_size,
                              hipStream_t stream) {
  const float* xyz     = (const float*)d_in[0];
  const float* centers = (const float*)d_in[1];
  const float* H4      = (const float*)d_in[2];
  const float* H8      = (const float*)d_in[3];
  const float* H12     = (const float*)d_in[4];
  const float* w1      = (const float*)d_in[5];
  const float* b1      = (const float*)d_in[6];
  const float* g1      = (const float*)d_in[7];
  const float* be1     = (const float*)d_in[8];
  const float* m1      = (const float*)d_in[9];
  const float* v1      = (const float*)d_in[10];
  const float* w2      = (const float*)d_in[11];
  const float* b2      = (const float*)d_in[12];
  const float* g2      = (const float*)d_in[13];
  const float* be2     = (const float*)d_in[14];
  const float* m2      = (const float*)d_in[15];
  const float* v2      = (const float*)d_in[16];
  float* outp = (float*)d_out;

  char* ws = (char*)d_ws;
  unsigned short* fusedb = (unsigned short*)(ws);                // 6,291,456 B
  unsigned short* w1b    = (unsigned short*)(ws + 6291456);      // 1,572,864 B
  unsigned short* w2b    = (unsigned short*)(ws + 7864320);      //   524,288 B
  float*          Amat   = (float*)         (ws + 8388608);      // 4,194,304 B
  unsigned short* h1     = (unsigned short*)(ws + 12582912);     // 33,554,432 B
  int*            nidx   = (int*)           (ws + 46137344);     //   393,216 B
  float*          nw     = (float*)         (ws + 46530560);     //   393,216 B
  float*          s1     = (float*)         (ws + 46923776);
  float* t1 = s1 + 512; float* s2 = t1 + 512; float* t2 = s2 + 512;

  prep_kernel<<<1025, 256, 0, stream>>>(w1, w2, g1, be1, m1, v1, g2, be2, m2, v2,
                                        w1b, w2b, s1, t1, s2, t2);
  cast_fused_kernel<<<3072, 256, 0, stream>>>(H4, H8, H12, fusedb);
  knn_kernel<<<dim3(128, 4), 256, 0, stream>>>(xyz, centers, nidx, nw);
  // Amat[m,n] = s1[n]*(fused.w1^T + b1[n]) + t1[n]  (relu deferred to interp)
  gemm1_kernel<<<256, 256, 0, stream>>>(fusedb, w1b, Amat, s1, b1, t1);
  interp_kernel<<<4096, 256, 0, stream>>>(Amat, nidx, nw, h1);
  // out = relu(s2*(h1.w2^T + b2) + t2)
  gemm2_kernel<<<1024, 256, 0, stream>>>(h1, w2b, outp, s2, b2, t2, 32768, 512, 512, 4);
}

// Round 5
// 188.441 us; speedup vs baseline: 1.1861x; 1.1861x over previous
//
#include <hip/hip_runtime.h>
#include <stdint.h>

// Problem constants: B=4, N=8192, G=512, E=512, D=3E=1536
#define NB 4
#define NP 8192
#define NG 512
#define DF 1536
#define NC 512

using f32x4   = __attribute__((ext_vector_type(4))) float;
using bf16x8  = __attribute__((ext_vector_type(8))) __bf16;
using ushort8v = __attribute__((ext_vector_type(8))) unsigned short;

// Swizzled bf16 operand layout ("fragment order"): matrix [R rows][K cols],
// R%16==0, K%32==0. Block b = (r>>4)*(K/32) + (k>>5) holds 16 rows x 32 k as
// 512 contiguous elems; within-block offset = lane*8 where
// lane = ((k>>3)&3)*16 + (r&15). A wave's MFMA fragment load (lane L -> row
// L&15, kofs (L>>4)*8) is then ONE contiguous 1KB global_load_dwordx4.

__device__ __forceinline__ unsigned short f32_to_bf16(float f) {
  unsigned int u = __float_as_uint(f);
  u += 0x7fffu + ((u >> 16) & 1u);   // round-to-nearest-even
  return (unsigned short)(u >> 16);
}

// ================= setup: knn + fused-cast-swizzle + w1/w2 swizzle + scales =
// grid layout: [0,512) knn | [512,2048) fused | [2048,2432) w1 | [2432,2560) w2
//              | 2560 scales
__global__ __launch_bounds__(256) void setup_kernel(
    const float* __restrict__ xyz, const float* __restrict__ centers,
    const float* __restrict__ H4, const float* __restrict__ H8,
    const float* __restrict__ H12,
    const float* __restrict__ w1, const float* __restrict__ w2,
    const float* __restrict__ g1, const float* __restrict__ be1,
    const float* __restrict__ m1, const float* __restrict__ v1,
    const float* __restrict__ g2, const float* __restrict__ be2,
    const float* __restrict__ m2, const float* __restrict__ v2,
    unsigned short* __restrict__ fswz, unsigned short* __restrict__ w1s,
    unsigned short* __restrict__ w2s,
    int* __restrict__ oidx, float* __restrict__ ow,
    float* __restrict__ s1, float* __restrict__ t1,
    float* __restrict__ s2, float* __restrict__ t2)
{
  __shared__ float4 cs[4 * 129];
  const int bx = blockIdx.x, tid = threadIdx.x;

  if (bx < 512) {
    // ---- KNN: 4 lanes/point, branchless top-3, shfl merge ----
    const int b = bx >> 7;
    for (int i = tid; i < NG; i += 256) {
      float c0 = centers[((size_t)b * NG + i) * 3 + 0];
      float c1 = centers[((size_t)b * NG + i) * 3 + 1];
      float c2 = centers[((size_t)b * NG + i) * 3 + 2];
      float4 v; v.x = c0; v.y = c1; v.z = c2; v.w = c0 * c0 + c1 * c1 + c2 * c2;
      cs[(i >> 7) * 129 + (i & 127)] = v;
    }
    __syncthreads();
    const int t = (bx & 127) * 256 + tid;
    const int p = t >> 2, q = t & 3;
    const size_t pi = (size_t)b * NP + p;
    const float x0 = xyz[pi * 3 + 0], x1 = xyz[pi * 3 + 1], x2 = xyz[pi * 3 + 2];
    const float xx = x0 * x0 + x1 * x1 + x2 * x2;
    float d0 = 3.4e38f, d1 = 3.4e38f, d2 = 3.4e38f;
    int i0 = 0, i1 = 0, i2 = 0;
    const int gbase = q * 128;
    const float4* csq = cs + q * 129;
#pragma unroll 4
    for (int j = 0; j < 128; ++j) {
      float4 c = csq[j];
      float d = xx + c.w - 2.0f * (x0 * c.x + x1 * c.y + x2 * c.z);
      int g = gbase + j;
      bool c0 = d < d0, c1 = d < d1, c2 = d < d2;
      float nd2 = c1 ? d1 : (c2 ? d : d2); int ni2 = c1 ? i1 : (c2 ? g : i2);
      float nd1 = c0 ? d0 : (c1 ? d : d1); int ni1 = c0 ? i0 : (c1 ? g : i1);
      d0 = c0 ? d : d0;                    i0 = c0 ? g : i0;
      d1 = nd1; i1 = ni1; d2 = nd2; i2 = ni2;
    }
#pragma unroll
    for (int off = 1; off <= 2; off <<= 1) {
      float e0 = __shfl_xor(d0, off), e1 = __shfl_xor(d1, off), e2 = __shfl_xor(d2, off);
      int j0 = __shfl_xor(i0, off), j1 = __shfl_xor(i1, off), j2 = __shfl_xor(i2, off);
#pragma unroll
      for (int s = 0; s < 3; ++s) {
        float e = (s == 0) ? e0 : (s == 1 ? e1 : e2);
        int   j = (s == 0) ? j0 : (s == 1 ? j1 : j2);
        bool c0 = (e < d0) || (e == d0 && j < i0);
        bool c1 = (e < d1) || (e == d1 && j < i1);
        bool c2 = (e < d2) || (e == d2 && j < i2);
        float nd2 = c1 ? d1 : (c2 ? e : d2); int ni2 = c1 ? i1 : (c2 ? j : i2);
        float nd1 = c0 ? d0 : (c1 ? e : d1); int ni1 = c0 ? i0 : (c1 ? j : i1);
        d0 = c0 ? e : d0;                    i0 = c0 ? j : i0;
        d1 = nd1; i1 = ni1; d2 = nd2; i2 = ni2;
      }
    }
    if (q == 0) {
      float r0 = 1.0f / (d0 + 1e-8f), r1 = 1.0f / (d1 + 1e-8f), r2 = 1.0f / (d2 + 1e-8f);
      float inv = 1.0f / (r0 + r1 + r2);
      ow[pi * 3 + 0] = r0 * inv; ow[pi * 3 + 1] = r1 * inv; ow[pi * 3 + 2] = r2 * inv;
      oidx[pi * 3 + 0] = i0; oidx[pi * 3 + 1] = i1; oidx[pi * 3 + 2] = i2;
    }
  } else if (bx < 2048) {
    // ---- fused=concat(H4,H8,H12) [2048,1536] f32 -> bf16 SWIZZLED ----
    const int qd = (bx - 512) * 256 + tid;   // < 393216
    const int L = qd & 63, t2 = qd >> 6;     // t2 < 6144
    const int kc = t2 % 48, mg = t2 / 48;    // mg < 128
    const int m = mg * 16 + (L & 15);
    const int k = kc * 32 + (L >> 4) * 8;
    const float* src = (k < 512) ? H4 : (k < 1024 ? H8 : H12);
    const float* sp = &src[(size_t)m * 512 + (k & 511)];
    float4 va = *(const float4*)sp, vb = *(const float4*)(sp + 4);
    ushort8v o;
    o[0] = f32_to_bf16(va.x); o[1] = f32_to_bf16(va.y);
    o[2] = f32_to_bf16(va.z); o[3] = f32_to_bf16(va.w);
    o[4] = f32_to_bf16(vb.x); o[5] = f32_to_bf16(vb.y);
    o[6] = f32_to_bf16(vb.z); o[7] = f32_to_bf16(vb.w);
    *(ushort8v*)&fswz[((size_t)(mg * 48 + kc)) * 512 + L * 8] = o;
  } else if (bx < 2432) {
    // ---- w1 [512,1536] f32 -> bf16 SWIZZLED ----
    const int qd = (bx - 2048) * 256 + tid;  // < 98304
    const int L = qd & 63, t2 = qd >> 6;     // t2 < 1536
    const int kc = t2 % 48, ng = t2 / 48;    // ng < 32
    const int n = ng * 16 + (L & 15);
    const int k = kc * 32 + (L >> 4) * 8;
    const float* sp = &w1[(size_t)n * 1536 + k];
    float4 va = *(const float4*)sp, vb = *(const float4*)(sp + 4);
    ushort8v o;
    o[0] = f32_to_bf16(va.x); o[1] = f32_to_bf16(va.y);
    o[2] = f32_to_bf16(va.z); o[3] = f32_to_bf16(va.w);
    o[4] = f32_to_bf16(vb.x); o[5] = f32_to_bf16(vb.y);
    o[6] = f32_to_bf16(vb.z); o[7] = f32_to_bf16(vb.w);
    *(ushort8v*)&w1s[((size_t)(ng * 48 + kc)) * 512 + L * 8] = o;
  } else if (bx < 2560) {
    // ---- w2 [512,512] f32 -> bf16 SWIZZLED ----
    const int qd = (bx - 2432) * 256 + tid;  // < 32768
    const int L = qd & 63, t2 = qd >> 6;     // t2 < 512
    const int kc = t2 & 15, ng = t2 >> 4;    // ng < 32
    const int n = ng * 16 + (L & 15);
    const int k = kc * 32 + (L >> 4) * 8;
    const float* sp = &w2[(size_t)n * 512 + k];
    float4 va = *(const float4*)sp, vb = *(const float4*)(sp + 4);
    ushort8v o;
    o[0] = f32_to_bf16(va.x); o[1] = f32_to_bf16(va.y);
    o[2] = f32_to_bf16(va.z); o[3] = f32_to_bf16(va.w);
    o[4] = f32_to_bf16(vb.x); o[5] = f32_to_bf16(vb.y);
    o[6] = f32_to_bf16(vb.z); o[7] = f32_to_bf16(vb.w);
    *(ushort8v*)&w2s[((size_t)(ng * 16 + kc)) * 512 + L * 8] = o;
  } else {
    // ---- BN constant folding ----
    for (int i = tid; i < 512; i += 256) {
      float sa = g1[i] / sqrtf(v1[i] + 1e-5f);
      s1[i] = sa; t1[i] = be1[i] - m1[i] * sa;
      float sb = g2[i] / sqrtf(v2[i] + 1e-5f);
      s2[i] = sb; t2[i] = be2[i] - m2[i] * sb;
    }
  }
}

// ================= GEMM1: Amat = s1*(fused.w1^T + b1) + t1 =================
// Swizzled operands, barrier-free wave-split-K (4 waves x K=384), 64x64 tile,
// 256 blocks. Fragment loads are contiguous 1KB/wave. LDS only for the
// 4-way cross-wave reduce.
__global__ __launch_bounds__(256) void gemm1_kernel(
    const unsigned short* __restrict__ Aswz, const unsigned short* __restrict__ Bswz,
    float* __restrict__ Amat,
    const float* __restrict__ svec, const float* __restrict__ bvec,
    const float* __restrict__ tvec)
{
  __shared__ float red[64 * 65];
  const int tid = threadIdx.x, lane = tid & 63, wv = tid >> 6;
  const int m0 = (blockIdx.x >> 3) * 64;
  const int n0 = (blockIdx.x & 7) * 64;

  // block index = (rowgrp)*48 + (wv*12 + kc); elem = block*512 + lane*8
  const unsigned short* Ap = Aswz + ((size_t)((m0 >> 4)) * 48 + wv * 12) * 512 + lane * 8;
  const unsigned short* Bp = Bswz + ((size_t)((n0 >> 4)) * 48 + wv * 12) * 512 + lane * 8;

  f32x4 acc[4][4];
#pragma unroll
  for (int i = 0; i < 4; ++i)
#pragma unroll
    for (int j = 0; j < 4; ++j) acc[i][j] = (f32x4){0.f, 0.f, 0.f, 0.f};

  bf16x8 af[4], bfr[4], afn[4], bfn[4];
#pragma unroll
  for (int i = 0; i < 4; ++i) {
    af[i]  = __builtin_bit_cast(bf16x8, *(const ushort8v*)(Ap + (size_t)i * 48 * 512));
    bfr[i] = __builtin_bit_cast(bf16x8, *(const ushort8v*)(Bp + (size_t)i * 48 * 512));
  }
#pragma unroll 1
  for (int kc = 0; kc < 12; ++kc) {
    if (kc < 11) {
#pragma unroll
      for (int i = 0; i < 4; ++i) {
        afn[i] = __builtin_bit_cast(bf16x8, *(const ushort8v*)(Ap + (size_t)i * 48 * 512 + (kc + 1) * 512));
        bfn[i] = __builtin_bit_cast(bf16x8, *(const ushort8v*)(Bp + (size_t)i * 48 * 512 + (kc + 1) * 512));
      }
    }
#pragma unroll
    for (int mi = 0; mi < 4; ++mi)
#pragma unroll
      for (int ni = 0; ni < 4; ++ni)
        acc[mi][ni] = __builtin_amdgcn_mfma_f32_16x16x32_bf16(af[mi], bfr[ni], acc[mi][ni], 0, 0, 0);
#pragma unroll
    for (int i = 0; i < 4; ++i) { af[i] = afn[i]; bfr[i] = bfn[i]; }
  }

  // 4-way cross-wave reduce through LDS
  for (int w = 0; w < 4; ++w) {
    if (wv == w) {
#pragma unroll
      for (int mi = 0; mi < 4; ++mi)
#pragma unroll
        for (int ni = 0; ni < 4; ++ni) {
          int col = ni * 16 + (lane & 15);
#pragma unroll
          for (int r = 0; r < 4; ++r) {
            int row = mi * 16 + (lane >> 4) * 4 + r;
            if (w == 0) red[row * 65 + col] = acc[mi][ni][r];
            else        red[row * 65 + col] += acc[mi][ni][r];
          }
        }
    }
    __syncthreads();
  }
  // epilogue: affine (relu deferred to interp), float4 stores, row-major
#pragma unroll
  for (int i = 0; i < 4; ++i) {
    int row = (tid >> 4) + i * 16;
    int col = (tid & 15) * 4;
    float4 v = *(const float4*)&red[row * 65 + col];
    int n = n0 + col;
    v.x = svec[n + 0] * (v.x + bvec[n + 0]) + tvec[n + 0];
    v.y = svec[n + 1] * (v.y + bvec[n + 1]) + tvec[n + 1];
    v.z = svec[n + 2] * (v.z + bvec[n + 2]) + tvec[n + 2];
    v.w = svec[n + 3] * (v.w + bvec[n + 3]) + tvec[n + 3];
    *(float4*)&Amat[(size_t)(m0 + row) * 512 + n] = v;
  }
}

// ================= interp: gather + weighted sum + ReLU -> h1 SWIZZLED ======
// Wave w handles point-group pg (16 points); loops 16 k-chunks of 32 channels.
// Writes are contiguous 1KB/wave in swizzled layout.
__global__ __launch_bounds__(256) void interp_kernel(
    const float* __restrict__ Amat, const int* __restrict__ nidx,
    const float* __restrict__ nw, unsigned short* __restrict__ h1s)
{
  const int lane = threadIdx.x & 63, wv = threadIdx.x >> 6;
  const int pg = blockIdx.x * 4 + wv;        // < 2048
  const int p = pg * 16 + (lane & 15);       // global point
  const int b = p >> 13;
  const int i0 = nidx[p * 3 + 0], i1 = nidx[p * 3 + 1], i2 = nidx[p * 3 + 2];
  const float w0 = nw[p * 3 + 0], w1v = nw[p * 3 + 1], w2v = nw[p * 3 + 2];
  const float* A0 = Amat + ((size_t)(b * 512 + i0)) * 512;
  const float* A1 = Amat + ((size_t)(b * 512 + i1)) * 512;
  const float* A2 = Amat + ((size_t)(b * 512 + i2)) * 512;
  const int cbase = (lane >> 4) * 8;
  unsigned short* wp = h1s + ((size_t)pg * 16) * 512 + lane * 8;
#pragma unroll 4
  for (int cc = 0; cc < 16; ++cc) {
    const int c = cc * 32 + cbase;
    float4 a0a = *(const float4*)&A0[c], a0b = *(const float4*)&A0[c + 4];
    float4 a1a = *(const float4*)&A1[c], a1b = *(const float4*)&A1[c + 4];
    float4 a2a = *(const float4*)&A2[c], a2b = *(const float4*)&A2[c + 4];
    ushort8v o;
    o[0] = f32_to_bf16(fmaxf(w0 * a0a.x + w1v * a1a.x + w2v * a2a.x, 0.f));
    o[1] = f32_to_bf16(fmaxf(w0 * a0a.y + w1v * a1a.y + w2v * a2a.y, 0.f));
    o[2] = f32_to_bf16(fmaxf(w0 * a0a.z + w1v * a1a.z + w2v * a2a.z, 0.f));
    o[3] = f32_to_bf16(fmaxf(w0 * a0a.w + w1v * a1a.w + w2v * a2a.w, 0.f));
    o[4] = f32_to_bf16(fmaxf(w0 * a0b.x + w1v * a1b.x + w2v * a2b.x, 0.f));
    o[5] = f32_to_bf16(fmaxf(w0 * a0b.y + w1v * a1b.y + w2v * a2b.y, 0.f));
    o[6] = f32_to_bf16(fmaxf(w0 * a0b.z + w1v * a1b.z + w2v * a2b.z, 0.f));
    o[7] = f32_to_bf16(fmaxf(w0 * a0b.w + w1v * a1b.w + w2v * a2b.w, 0.f));
    *(ushort8v*)(wp + (size_t)cc * 512) = o;
  }
}

// ================= GEMM2: out = relu(s2*(h1.w2^T + b2) + t2) ================
// Swizzled operands, barrier-free, LDS-free. 128x128 tile, 4 waves 2x2,
// contiguous 1KB/wave fragment loads, 1-deep register prefetch.
__global__ __launch_bounds__(256) void gemm2_kernel(
    const unsigned short* __restrict__ Aswz, const unsigned short* __restrict__ Bswz,
    float* __restrict__ outp,
    const float* __restrict__ svec, const float* __restrict__ bvec,
    const float* __restrict__ tvec)
{
  const int tid = threadIdx.x, lane = tid & 63, wv = tid >> 6;
  const int wm = wv >> 1, wn = wv & 1;
  // XCD-aware swizzle: xcd owns contiguous M range -> A-tile L2 reuse
  const int L = blockIdx.x;
  const int xcd = L & 7, slot = L >> 3;
  const int mloc = slot >> 2, nt = slot & 3;    // 32 m-tiles/XCD, 4 n-tiles
  const int m0 = (xcd * 32 + mloc) * 128, n0 = nt * 128;

  // block idx = (rowgrp)*16 + kc ; elem = block*512 + lane*8
  const unsigned short* Ap = Aswz + ((size_t)((m0 >> 4) + wm * 4) * 16) * 512 + lane * 8;
  const unsigned short* Bp = Bswz + ((size_t)((n0 >> 4) + wn * 4) * 16) * 512 + lane * 8;

  f32x4 acc[4][4];
#pragma unroll
  for (int i = 0; i < 4; ++i)
#pragma unroll
    for (int j = 0; j < 4; ++j) acc[i][j] = (f32x4){0.f, 0.f, 0.f, 0.f};

  bf16x8 af[4], bfr[4], afn[4], bfn[4];
#pragma unroll
  for (int i = 0; i < 4; ++i) {
    af[i]  = __builtin_bit_cast(bf16x8, *(const ushort8v*)(Ap + (size_t)i * 16 * 512));
    bfr[i] = __builtin_bit_cast(bf16x8, *(const ushort8v*)(Bp + (size_t)i * 16 * 512));
  }
#pragma unroll 1
  for (int kc = 0; kc < 16; ++kc) {
    if (kc < 15) {
#pragma unroll
      for (int i = 0; i < 4; ++i) {
        afn[i] = __builtin_bit_cast(bf16x8, *(const ushort8v*)(Ap + (size_t)i * 16 * 512 + (kc + 1) * 512));
        bfn[i] = __builtin_bit_cast(bf16x8, *(const ushort8v*)(Bp + (size_t)i * 16 * 512 + (kc + 1) * 512));
      }
    }
#pragma unroll
    for (int mi = 0; mi < 4; ++mi)
#pragma unroll
      for (int ni = 0; ni < 4; ++ni)
        acc[mi][ni] = __builtin_amdgcn_mfma_f32_16x16x32_bf16(af[mi], bfr[ni], acc[mi][ni], 0, 0, 0);
#pragma unroll
    for (int i = 0; i < 4; ++i) { af[i] = afn[i]; bfr[i] = bfn[i]; }
  }

  // C/D layout: n = lane&15, m = (lane>>4)*4 + reg   [m89-verified]
#pragma unroll
  for (int mi = 0; mi < 4; ++mi) {
    int mbase = m0 + wm * 64 + mi * 16 + (lane >> 4) * 4;
#pragma unroll
    for (int ni = 0; ni < 4; ++ni) {
      int n = n0 + wn * 64 + ni * 16 + (lane & 15);
      float s = svec[n], bb = bvec[n], t = tvec[n];
      f32x4 v = acc[mi][ni];
#pragma unroll
      for (int r = 0; r < 4; ++r) {
        float val = fmaxf(s * (v[r] + bb) + t, 0.f);
        outp[(size_t)(mbase + r) * 512 + n] = val;
      }
    }
  }
}

extern "C" void kernel_launch(void* const* d_in, const int* in_sizes, int n_in,
                              void* d_out, int out_size, void* d_ws, size_t ws_size,
                              hipStream_t stream) {
  const float* xyz     = (const float*)d_in[0];
  const float* centers = (const float*)d_in[1];
  const float* H4      = (const float*)d_in[2];
  const float* H8      = (const float*)d_in[3];
  const float* H12     = (const float*)d_in[4];
  const float* w1      = (const float*)d_in[5];
  const float* b1      = (const float*)d_in[6];
  const float* g1      = (const float*)d_in[7];
  const float* be1     = (const float*)d_in[8];
  const float* m1      = (const float*)d_in[9];
  const float* v1      = (const float*)d_in[10];
  const float* w2      = (const float*)d_in[11];
  const float* b2      = (const float*)d_in[12];
  const float* g2      = (const float*)d_in[13];
  const float* be2     = (const float*)d_in[14];
  const float* m2      = (const float*)d_in[15];
  const float* v2      = (const float*)d_in[16];
  float* outp = (float*)d_out;

  char* ws = (char*)d_ws;
  unsigned short* fswz = (unsigned short*)(ws);                // 6,291,456 B
  unsigned short* w1s  = (unsigned short*)(ws + 6291456);      // 1,572,864 B
  unsigned short* w2s  = (unsigned short*)(ws + 7864320);      //   524,288 B
  float*          Amat = (float*)         (ws + 8388608);      // 4,194,304 B
  unsigned short* h1s  = (unsigned short*)(ws + 12582912);     // 33,554,432 B
  int*            nidx = (int*)           (ws + 46137344);     //   393,216 B
  float*          nw   = (float*)         (ws + 46530560);     //   393,216 B
  float*          s1   = (float*)         (ws + 46923776);
  float* t1 = s1 + 512; float* s2 = t1 + 512; float* t2 = s2 + 512;

  setup_kernel<<<2561, 256, 0, stream>>>(
      xyz, centers, H4, H8, H12, w1, w2,
      g1, be1, m1, v1, g2, be2, m2, v2,
      fswz, w1s, w2s, nidx, nw, s1, t1, s2, t2);
  gemm1_kernel<<<256, 256, 0, stream>>>(fswz, w1s, Amat, s1, b1, t1);
  interp_kernel<<<512, 256, 0, stream>>>(Amat, nidx, nw, h1s);
  gemm2_kernel<<<1024, 256, 0, stream>>>(h1s, w2s, outp, s2, b2, t2);
}

// Round 7
// 177.997 us; speedup vs baseline: 1.2556x; 1.0587x over previous
//
#include <hip/hip_runtime.h>
#include <hip/hip_cooperative_groups.h>
#include <stdint.h>

// Problem constants: B=4, N=8192, G=512, E=512, D=3E=1536
#define NP 8192
#define NG 512
#define DF 1536

namespace cg = cooperative_groups;

using f32x4    = __attribute__((ext_vector_type(4))) float;
using bf16x8   = __attribute__((ext_vector_type(8))) __bf16;
using ushort8v = __attribute__((ext_vector_type(8))) unsigned short;

// Swizzled bf16 operand layout ("fragment order"): matrix [R rows][K cols],
// block b = (r>>4)*(K/32) + (k>>5) holds 16 rows x 32 k as 512 contiguous
// elems; offset = lane*8, lane = ((k>>3)&3)*16 + (r&15). A wave's MFMA
// fragment load is then ONE contiguous 1KB global_load_dwordx4.

__device__ __forceinline__ unsigned short f32_to_bf16(float f) {
  unsigned int u = __float_as_uint(f);
  u += 0x7fffu + ((u >> 16) & 1u);   // round-to-nearest-even
  return (unsigned short)(u >> 16);
}
__device__ __forceinline__ float bf2f(unsigned short u) {
  return __uint_as_float(((unsigned)u) << 16);
}

struct FusedArgs {
  const float *xyz, *centers, *H4, *H8, *H12, *w1, *w2;
  const float *g1, *be1, *m1, *v1, *g2, *be2, *m2, *v2, *b1, *b2;
  unsigned short *fswz, *w1s, *w2s, *Amatb, *h1s;
  int *nidx; float *nw, *s1, *t1, *s2, *t2;
  float *outp;
};

// ============ Phase 1 unit: knn / swizzle-casts / BN fold ===================
// units: [0,512) knn | [512,2048) fused | [2048,2432) w1 | [2432,2560) w2 | 2560 scales
__device__ void phase_setup(const FusedArgs& a, char* smem, int w) {
  const int tid = threadIdx.x;
  if (w < 512) {
    // ---- KNN: 4 lanes/point, branchless top-3, shfl merge ----
    float4* cs = (float4*)smem;            // [4*129]
    const int b = w >> 7;
    for (int i = tid; i < NG; i += 256) {
      float c0 = a.centers[((size_t)b * NG + i) * 3 + 0];
      float c1 = a.centers[((size_t)b * NG + i) * 3 + 1];
      float c2 = a.centers[((size_t)b * NG + i) * 3 + 2];
      float4 v; v.x = c0; v.y = c1; v.z = c2; v.w = c0 * c0 + c1 * c1 + c2 * c2;
      cs[(i >> 7) * 129 + (i & 127)] = v;
    }
    __syncthreads();
    const int t = (w & 127) * 256 + tid;
    const int p = t >> 2, q = t & 3;
    const size_t pi = (size_t)b * NP + p;
    const float x0 = a.xyz[pi * 3 + 0], x1 = a.xyz[pi * 3 + 1], x2 = a.xyz[pi * 3 + 2];
    const float xx = x0 * x0 + x1 * x1 + x2 * x2;
    float d0 = 3.4e38f, d1 = 3.4e38f, d2 = 3.4e38f;
    int i0 = 0, i1 = 0, i2 = 0;
    const int gbase = q * 128;
    const float4* csq = cs + q * 129;
#pragma unroll 4
    for (int j = 0; j < 128; ++j) {
      float4 c = csq[j];
      float d = xx + c.w - 2.0f * (x0 * c.x + x1 * c.y + x2 * c.z);
      int g = gbase + j;
      bool c0 = d < d0, c1 = d < d1, c2 = d < d2;
      float nd2 = c1 ? d1 : (c2 ? d : d2); int ni2 = c1 ? i1 : (c2 ? g : i2);
      float nd1 = c0 ? d0 : (c1 ? d : d1); int ni1 = c0 ? i0 : (c1 ? g : i1);
      d0 = c0 ? d : d0;                    i0 = c0 ? g : i0;
      d1 = nd1; i1 = ni1; d2 = nd2; i2 = ni2;
    }
#pragma unroll
    for (int off = 1; off <= 2; off <<= 1) {
      float e0 = __shfl_xor(d0, off), e1 = __shfl_xor(d1, off), e2 = __shfl_xor(d2, off);
      int j0 = __shfl_xor(i0, off), j1 = __shfl_xor(i1, off), j2 = __shfl_xor(i2, off);
#pragma unroll
      for (int s = 0; s < 3; ++s) {
        float e = (s == 0) ? e0 : (s == 1 ? e1 : e2);
        int   j = (s == 0) ? j0 : (s == 1 ? j1 : j2);
        bool c0 = (e < d0) || (e == d0 && j < i0);
        bool c1 = (e < d1) || (e == d1 && j < i1);
        bool c2 = (e < d2) || (e == d2 && j < i2);
        float nd2 = c1 ? d1 : (c2 ? e : d2); int ni2 = c1 ? i1 : (c2 ? j : i2);
        float nd1 = c0 ? d0 : (c1 ? e : d1); int ni1 = c0 ? i0 : (c1 ? j : i1);
        d0 = c0 ? e : d0;                    i0 = c0 ? j : i0;
        d1 = nd1; i1 = ni1; d2 = nd2; i2 = ni2;
      }
    }
    if (q == 0) {
      float r0 = 1.0f / (d0 + 1e-8f), r1 = 1.0f / (d1 + 1e-8f), r2 = 1.0f / (d2 + 1e-8f);
      float inv = 1.0f / (r0 + r1 + r2);
      a.nw[pi * 3 + 0] = r0 * inv; a.nw[pi * 3 + 1] = r1 * inv; a.nw[pi * 3 + 2] = r2 * inv;
      a.nidx[pi * 3 + 0] = i0; a.nidx[pi * 3 + 1] = i1; a.nidx[pi * 3 + 2] = i2;
    }
    __syncthreads();
  } else if (w < 2048) {
    // ---- fused=concat(H4,H8,H12) [2048,1536] f32 -> bf16 SWIZZLED ----
    const int qd = (w - 512) * 256 + tid;
    const int L = qd & 63, t2 = qd >> 6;
    const int kc = t2 % 48, mg = t2 / 48;
    const int m = mg * 16 + (L & 15);
    const int k = kc * 32 + (L >> 4) * 8;
    const float* src = (k < 512) ? a.H4 : (k < 1024 ? a.H8 : a.H12);
    const float* sp = &src[(size_t)m * 512 + (k & 511)];
    float4 va = *(const float4*)sp, vb = *(const float4*)(sp + 4);
    ushort8v o;
    o[0] = f32_to_bf16(va.x); o[1] = f32_to_bf16(va.y);
    o[2] = f32_to_bf16(va.z); o[3] = f32_to_bf16(va.w);
    o[4] = f32_to_bf16(vb.x); o[5] = f32_to_bf16(vb.y);
    o[6] = f32_to_bf16(vb.z); o[7] = f32_to_bf16(vb.w);
    *(ushort8v*)&a.fswz[((size_t)(mg * 48 + kc)) * 512 + L * 8] = o;
  } else if (w < 2432) {
    // ---- w1 [512,1536] -> bf16 SWIZZLED ----
    const int qd = (w - 2048) * 256 + tid;
    const int L = qd & 63, t2 = qd >> 6;
    const int kc = t2 % 48, ng = t2 / 48;
    const int n = ng * 16 + (L & 15);
    const int k = kc * 32 + (L >> 4) * 8;
    const float* sp = &a.w1[(size_t)n * 1536 + k];
    float4 va = *(const float4*)sp, vb = *(const float4*)(sp + 4);
    ushort8v o;
    o[0] = f32_to_bf16(va.x); o[1] = f32_to_bf16(va.y);
    o[2] = f32_to_bf16(va.z); o[3] = f32_to_bf16(va.w);
    o[4] = f32_to_bf16(vb.x); o[5] = f32_to_bf16(vb.y);
    o[6] = f32_to_bf16(vb.z); o[7] = f32_to_bf16(vb.w);
    *(ushort8v*)&a.w1s[((size_t)(ng * 48 + kc)) * 512 + L * 8] = o;
  } else if (w < 2560) {
    // ---- w2 [512,512] -> bf16 SWIZZLED ----
    const int qd = (w - 2432) * 256 + tid;
    const int L = qd & 63, t2 = qd >> 6;
    const int kc = t2 & 15, ng = t2 >> 4;
    const int n = ng * 16 + (L & 15);
    const int k = kc * 32 + (L >> 4) * 8;
    const float* sp = &a.w2[(size_t)n * 512 + k];
    float4 va = *(const float4*)sp, vb = *(const float4*)(sp + 4);
    ushort8v o;
    o[0] = f32_to_bf16(va.x); o[1] = f32_to_bf16(va.y);
    o[2] = f32_to_bf16(va.z); o[3] = f32_to_bf16(va.w);
    o[4] = f32_to_bf16(vb.x); o[5] = f32_to_bf16(vb.y);
    o[6] = f32_to_bf16(vb.z); o[7] = f32_to_bf16(vb.w);
    *(ushort8v*)&a.w2s[((size_t)(ng * 16 + kc)) * 512 + L * 8] = o;
  } else {
    // ---- BN constant folding ----
    for (int i = tid; i < 512; i += 256) {
      float sa = a.g1[i] / sqrtf(a.v1[i] + 1e-5f);
      a.s1[i] = sa; a.t1[i] = a.be1[i] - a.m1[i] * sa;
      float sb = a.g2[i] / sqrtf(a.v2[i] + 1e-5f);
      a.s2[i] = sb; a.t2[i] = a.be2[i] - a.m2[i] * sb;
    }
  }
}

// ============ Phase 2: GEMM1  Amatb = bf16(s1*(fused.w1^T + b1) + t1) =======
// 512 blocks, 32x64 tile, barrier-free wave-split-K (4 waves x K=384).
__device__ void phase_gemm1(const FusedArgs& a, char* smem) {
  float* red = (float*)smem;               // [32*65]
  const int tid = threadIdx.x, lane = tid & 63, wv = tid >> 6;
  const int blk = blockIdx.x;
  const int m0 = (blk >> 3) * 32;
  const int n0 = (blk & 7) * 64;
  const unsigned short* Ap = a.fswz + ((size_t)(m0 >> 4) * 48 + wv * 12) * 512 + lane * 8;
  const unsigned short* Bp = a.w1s  + ((size_t)(n0 >> 4) * 48 + wv * 12) * 512 + lane * 8;

  f32x4 acc[2][4];
#pragma unroll
  for (int i = 0; i < 2; ++i)
#pragma unroll
    for (int j = 0; j < 4; ++j) acc[i][j] = (f32x4){0.f, 0.f, 0.f, 0.f};

  bf16x8 af[2], bfr[4], afn[2], bfn[4];
#pragma unroll
  for (int i = 0; i < 2; ++i)
    af[i]  = __builtin_bit_cast(bf16x8, *(const ushort8v*)(Ap + (size_t)i * 48 * 512));
#pragma unroll
  for (int i = 0; i < 4; ++i)
    bfr[i] = __builtin_bit_cast(bf16x8, *(const ushort8v*)(Bp + (size_t)i * 48 * 512));
#pragma unroll 1
  for (int kc = 0; kc < 12; ++kc) {
    if (kc < 11) {
#pragma unroll
      for (int i = 0; i < 2; ++i)
        afn[i] = __builtin_bit_cast(bf16x8, *(const ushort8v*)(Ap + (size_t)i * 48 * 512 + (kc + 1) * 512));
#pragma unroll
      for (int i = 0; i < 4; ++i)
        bfn[i] = __builtin_bit_cast(bf16x8, *(const ushort8v*)(Bp + (size_t)i * 48 * 512 + (kc + 1) * 512));
    }
#pragma unroll
    for (int mi = 0; mi < 2; ++mi)
#pragma unroll
      for (int ni = 0; ni < 4; ++ni)
        acc[mi][ni] = __builtin_amdgcn_mfma_f32_16x16x32_bf16(af[mi], bfr[ni], acc[mi][ni], 0, 0, 0);
#pragma unroll
    for (int i = 0; i < 2; ++i) af[i] = afn[i];
#pragma unroll
    for (int i = 0; i < 4; ++i) bfr[i] = bfn[i];
  }

  // 4-way cross-wave reduce through LDS
  for (int w = 0; w < 4; ++w) {
    if (wv == w) {
#pragma unroll
      for (int mi = 0; mi < 2; ++mi)
#pragma unroll
        for (int ni = 0; ni < 4; ++ni) {
          int col = ni * 16 + (lane & 15);
#pragma unroll
          for (int r = 0; r < 4; ++r) {
            int row = mi * 16 + (lane >> 4) * 4 + r;
            if (w == 0) red[row * 65 + col] = acc[mi][ni][r];
            else        red[row * 65 + col] += acc[mi][ni][r];
          }
        }
    }
    __syncthreads();
  }
  // epilogue: affine -> bf16 (relu deferred to interp), 16B stores
  const int row = tid >> 3;               // 0..31
  const int col = (tid & 7) * 8;          // 0..56
  ushort8v o;
#pragma unroll
  for (int j = 0; j < 8; ++j) {
    int n = n0 + col + j;
    float v = red[row * 65 + col + j];
    o[j] = f32_to_bf16(a.s1[n] * (v + a.b1[n]) + a.t1[n]);
  }
  *(ushort8v*)&a.Amatb[(size_t)(m0 + row) * 512 + n0 + col] = o;
}

// ============ Phase 3: interp  h1s = bf16(relu(sum_k w_k*Amatb[idx_k])) =====
// 2048 wave-units (512 blocks x 4 waves): one 16-point group per wave.
__device__ void phase_interp(const FusedArgs& a) {
  const int tid = threadIdx.x, lane = tid & 63, wv = tid >> 6;
  const int pg = blockIdx.x * 4 + wv;        // < 2048
  const int p = pg * 16 + (lane & 15);
  const int b = p >> 13;
  const int i0 = a.nidx[p * 3 + 0], i1 = a.nidx[p * 3 + 1], i2 = a.nidx[p * 3 + 2];
  const float w0 = a.nw[p * 3 + 0], w1v = a.nw[p * 3 + 1], w2v = a.nw[p * 3 + 2];
  const unsigned short* A0 = a.Amatb + ((size_t)(b * 512 + i0)) * 512;
  const unsigned short* A1 = a.Amatb + ((size_t)(b * 512 + i1)) * 512;
  const unsigned short* A2 = a.Amatb + ((size_t)(b * 512 + i2)) * 512;
  const int cbase = (lane >> 4) * 8;
  unsigned short* wp = a.h1s + ((size_t)pg * 16) * 512 + lane * 8;
#pragma unroll 4
  for (int cc = 0; cc < 16; ++cc) {
    const int c = cc * 32 + cbase;
    ushort8v u0 = *(const ushort8v*)&A0[c];
    ushort8v u1 = *(const ushort8v*)&A1[c];
    ushort8v u2 = *(const ushort8v*)&A2[c];
    ushort8v o;
#pragma unroll
    for (int j = 0; j < 8; ++j) {
      float v = w0 * bf2f(u0[j]) + w1v * bf2f(u1[j]) + w2v * bf2f(u2[j]);
      o[j] = f32_to_bf16(fmaxf(v, 0.f));
    }
    *(ushort8v*)(wp + (size_t)cc * 512) = o;
  }
}

// ============ Phase 4: GEMM2 tile L: out = relu(s2*(h1.w2^T + b2) + t2) =====
// 1024 tiles 128x128, 4 waves 2x2, barrier-free swizzled fragment loads.
__device__ void phase_gemm2(const FusedArgs& a, int L) {
  const int tid = threadIdx.x, lane = tid & 63, wv = tid >> 6;
  const int wm = wv >> 1, wn = wv & 1;
  const int xcd = L & 7, slot = L >> 3;
  const int mloc = slot >> 2, nt = slot & 3;
  const int m0 = (xcd * 32 + mloc) * 128, n0 = nt * 128;

  const unsigned short* Ap = a.h1s + ((size_t)((m0 >> 4) + wm * 4) * 16) * 512 + lane * 8;
  const unsigned short* Bp = a.w2s + ((size_t)((n0 >> 4) + wn * 4) * 16) * 512 + lane * 8;

  f32x4 acc[4][4];
#pragma unroll
  for (int i = 0; i < 4; ++i)
#pragma unroll
    for (int j = 0; j < 4; ++j) acc[i][j] = (f32x4){0.f, 0.f, 0.f, 0.f};

  bf16x8 af[4], bfr[4], afn[4], bfn[4];
#pragma unroll
  for (int i = 0; i < 4; ++i) {
    af[i]  = __builtin_bit_cast(bf16x8, *(const ushort8v*)(Ap + (size_t)i * 16 * 512));
    bfr[i] = __builtin_bit_cast(bf16x8, *(const ushort8v*)(Bp + (size_t)i * 16 * 512));
  }
#pragma unroll 1
  for (int kc = 0; kc < 16; ++kc) {
    if (kc < 15) {
#pragma unroll
      for (int i = 0; i < 4; ++i) {
        afn[i] = __builtin_bit_cast(bf16x8, *(const ushort8v*)(Ap + (size_t)i * 16 * 512 + (kc + 1) * 512));
        bfn[i] = __builtin_bit_cast(bf16x8, *(const ushort8v*)(Bp + (size_t)i * 16 * 512 + (kc + 1) * 512));
      }
    }
#pragma unroll
    for (int mi = 0; mi < 4; ++mi)
#pragma unroll
      for (int ni = 0; ni < 4; ++ni)
        acc[mi][ni] = __builtin_amdgcn_mfma_f32_16x16x32_bf16(af[mi], bfr[ni], acc[mi][ni], 0, 0, 0);
#pragma unroll
    for (int i = 0; i < 4; ++i) { af[i] = afn[i]; bfr[i] = bfn[i]; }
  }

  // C/D layout: n = lane&15, m = (lane>>4)*4 + reg   [m89-verified]
#pragma unroll
  for (int mi = 0; mi < 4; ++mi) {
    int mbase = m0 + wm * 64 + mi * 16 + (lane >> 4) * 4;
#pragma unroll
    for (int ni = 0; ni < 4; ++ni) {
      int n = n0 + wn * 64 + ni * 16 + (lane & 15);
      float s = a.s2[n], bb = a.b2[n], t = a.t2[n];
      f32x4 v = acc[mi][ni];
#pragma unroll
      for (int r = 0; r < 4; ++r) {
        float val = fmaxf(s * (v[r] + bb) + t, 0.f);
        a.outp[(size_t)(mbase + r) * 512 + n] = val;
      }
    }
  }
}

// ============ cooperative fused kernel: 512 blocks, 2 blocks/CU =============
__global__ __launch_bounds__(256, 2) void fused_kernel(FusedArgs a) {
  __shared__ __align__(16) char smem[8448];
  cg::grid_group grid = cg::this_grid();
  const int blk = blockIdx.x;
  for (int u = blk; u <= 2560; u += 512) phase_setup(a, smem, u);
  grid.sync();
  phase_gemm1(a, smem);
  grid.sync();
  phase_interp(a);
  grid.sync();
  phase_gemm2(a, blk);
  phase_gemm2(a, blk + 512);
}

// ============ fallback standalone kernels (same device code) ================
__global__ __launch_bounds__(256) void k_setup(FusedArgs a) {
  __shared__ __align__(16) char smem[8448];
  for (int u = blockIdx.x; u <= 2560; u += 512) phase_setup(a, smem, u);
}
__global__ __launch_bounds__(256) void k_gemm1(FusedArgs a) {
  __shared__ __align__(16) char smem[8448];
  phase_gemm1(a, smem);
}
__global__ __launch_bounds__(256) void k_interp(FusedArgs a) { phase_interp(a); }
__global__ __launch_bounds__(256) void k_gemm2(FusedArgs a) {
  phase_gemm2(a, blockIdx.x);
  phase_gemm2(a, blockIdx.x + 512);
}

extern "C" void kernel_launch(void* const* d_in, const int* in_sizes, int n_in,
                              void* d_out, int out_size, void* d_ws, size_t ws_size,
                              hipStream_t stream) {
  char* ws = (char*)d_ws;
  FusedArgs a;
  a.xyz     = (const float*)d_in[0];
  a.centers = (const float*)d_in[1];
  a.H4      = (const float*)d_in[2];
  a.H8      = (const float*)d_in[3];
  a.H12     = (const float*)d_in[4];
  a.w1      = (const float*)d_in[5];
  a.b1      = (const float*)d_in[6];
  a.g1      = (const float*)d_in[7];
  a.be1     = (const float*)d_in[8];
  a.m1      = (const float*)d_in[9];
  a.v1      = (const float*)d_in[10];
  a.w2      = (const float*)d_in[11];
  a.b2      = (const float*)d_in[12];
  a.g2      = (const float*)d_in[13];
  a.be2     = (const float*)d_in[14];
  a.m2      = (const float*)d_in[15];
  a.v2      = (const float*)d_in[16];
  a.fswz  = (unsigned short*)(ws);                // 6,291,456 B
  a.w1s   = (unsigned short*)(ws + 6291456);      // 1,572,864 B
  a.w2s   = (unsigned short*)(ws + 7864320);      //   524,288 B
  a.Amatb = (unsigned short*)(ws + 8388608);      // 2,097,152 B (bf16)
  a.h1s   = (unsigned short*)(ws + 12582912);     // 33,554,432 B
  a.nidx  = (int*)           (ws + 46137344);     //   393,216 B
  a.nw    = (float*)         (ws + 46530560);     //   393,216 B
  a.s1    = (float*)         (ws + 46923776);
  a.t1 = a.s1 + 512; a.s2 = a.t1 + 512; a.t2 = a.s2 + 512;
  a.outp  = (float*)d_out;

  // Occupancy-gated cooperative launch: pure host query (capture-safe).
  int nb = 0;
  hipError_t qerr = hipOccupancyMaxActiveBlocksPerMultiprocessor(
      &nb, reinterpret_cast<const void*>(fused_kernel), 256, 0);
  bool coop_ok = (qerr == hipSuccess) && (nb >= 2);
  if (coop_ok) {
    void* kp[] = { (void*)&a };
    hipError_t lerr = hipLaunchCooperativeKernel(
        (const void*)fused_kernel, dim3(512), dim3(256), kp, 0, stream);
    coop_ok = (lerr == hipSuccess);
  }
  if (!coop_ok) {
    k_setup <<<512, 256, 0, stream>>>(a);
    k_gemm1 <<<512, 256, 0, stream>>>(a);
    k_interp<<<512, 256, 0, stream>>>(a);
    k_gemm2 <<<512, 256, 0, stream>>>(a);
  }
}

// Round 8
// 166.770 us; speedup vs baseline: 1.3402x; 1.0673x over previous
//
#include <hip/hip_runtime.h>
#include <hip/hip_cooperative_groups.h>
#include <stdint.h>

// Problem constants: B=4, N=8192, G=512, E=512, D=3E=1536
#define NP 8192
#define NG 512
#define DF 1536

namespace cg = cooperative_groups;

using f32x4    = __attribute__((ext_vector_type(4))) float;
using bf16x8   = __attribute__((ext_vector_type(8))) __bf16;
using ushort8v = __attribute__((ext_vector_type(8))) unsigned short;

// Swizzled bf16 operand layout ("fragment order"): matrix [R rows][K cols],
// block b = (r>>4)*(K/32) + (k>>5) holds 16 rows x 32 k as 512 contiguous
// elems; offset = lane*8, lane = ((k>>3)&3)*16 + (r&15). A wave's MFMA
// fragment load is then ONE contiguous 1KB global_load_dwordx4 (or ds_read_b128).

__device__ __forceinline__ unsigned short f32_to_bf16(float f) {
  unsigned int u = __float_as_uint(f);
  u += 0x7fffu + ((u >> 16) & 1u);   // round-to-nearest-even
  return (unsigned short)(u >> 16);
}
__device__ __forceinline__ float bf2f(unsigned short u) {
  return __uint_as_float(((unsigned)u) << 16);
}

struct FusedArgs {
  const float *xyz, *centers, *H4, *H8, *H12, *w1, *w2;
  const float *g1, *be1, *m1, *v1, *g2, *be2, *m2, *v2, *b1, *b2;
  unsigned short *fswz, *w1s, *w2s, *Amatb;
  int *nidx; float *nw, *s1, *t1, *s2, *t2;
  float *outp;
};

// ============ Phase 1 unit: knn / swizzle-casts / BN fold ===================
// units: [0,512) knn | [512,2048) fused | [2048,2432) w1 | [2432,2560) w2 | 2560 scales
__device__ void phase_setup(const FusedArgs& a, char* smem, int w) {
  const int tid = threadIdx.x;
  if (w < 512) {
    // ---- KNN: 4 lanes/point, branchless top-3, shfl merge ----
    float4* cs = (float4*)smem;            // [4*129]
    const int b = w >> 7;
    for (int i = tid; i < NG; i += 256) {
      float c0 = a.centers[((size_t)b * NG + i) * 3 + 0];
      float c1 = a.centers[((size_t)b * NG + i) * 3 + 1];
      float c2 = a.centers[((size_t)b * NG + i) * 3 + 2];
      float4 v; v.x = c0; v.y = c1; v.z = c2; v.w = c0 * c0 + c1 * c1 + c2 * c2;
      cs[(i >> 7) * 129 + (i & 127)] = v;
    }
    __syncthreads();
    const int t = (w & 127) * 256 + tid;
    const int p = t >> 2, q = t & 3;
    const size_t pi = (size_t)b * NP + p;
    const float x0 = a.xyz[pi * 3 + 0], x1 = a.xyz[pi * 3 + 1], x2 = a.xyz[pi * 3 + 2];
    const float xx = x0 * x0 + x1 * x1 + x2 * x2;
    float d0 = 3.4e38f, d1 = 3.4e38f, d2 = 3.4e38f;
    int i0 = 0, i1 = 0, i2 = 0;
    const int gbase = q * 128;
    const float4* csq = cs + q * 129;
#pragma unroll 4
    for (int j = 0; j < 128; ++j) {
      float4 c = csq[j];
      float d = xx + c.w - 2.0f * (x0 * c.x + x1 * c.y + x2 * c.z);
      int g = gbase + j;
      bool c0 = d < d0, c1 = d < d1, c2 = d < d2;
      float nd2 = c1 ? d1 : (c2 ? d : d2); int ni2 = c1 ? i1 : (c2 ? g : i2);
      float nd1 = c0 ? d0 : (c1 ? d : d1); int ni1 = c0 ? i0 : (c1 ? g : i1);
      d0 = c0 ? d : d0;                    i0 = c0 ? g : i0;
      d1 = nd1; i1 = ni1; d2 = nd2; i2 = ni2;
    }
#pragma unroll
    for (int off = 1; off <= 2; off <<= 1) {
      float e0 = __shfl_xor(d0, off), e1 = __shfl_xor(d1, off), e2 = __shfl_xor(d2, off);
      int j0 = __shfl_xor(i0, off), j1 = __shfl_xor(i1, off), j2 = __shfl_xor(i2, off);
#pragma unroll
      for (int s = 0; s < 3; ++s) {
        float e = (s == 0) ? e0 : (s == 1 ? e1 : e2);
        int   j = (s == 0) ? j0 : (s == 1 ? j1 : j2);
        bool c0 = (e < d0) || (e == d0 && j < i0);
        bool c1 = (e < d1) || (e == d1 && j < i1);
        bool c2 = (e < d2) || (e == d2 && j < i2);
        float nd2 = c1 ? d1 : (c2 ? e : d2); int ni2 = c1 ? i1 : (c2 ? j : i2);
        float nd1 = c0 ? d0 : (c1 ? e : d1); int ni1 = c0 ? i0 : (c1 ? j : i1);
        d0 = c0 ? e : d0;                    i0 = c0 ? j : i0;
        d1 = nd1; i1 = ni1; d2 = nd2; i2 = ni2;
      }
    }
    if (q == 0) {
      float r0 = 1.0f / (d0 + 1e-8f), r1 = 1.0f / (d1 + 1e-8f), r2 = 1.0f / (d2 + 1e-8f);
      float inv = 1.0f / (r0 + r1 + r2);
      a.nw[pi * 3 + 0] = r0 * inv; a.nw[pi * 3 + 1] = r1 * inv; a.nw[pi * 3 + 2] = r2 * inv;
      a.nidx[pi * 3 + 0] = i0; a.nidx[pi * 3 + 1] = i1; a.nidx[pi * 3 + 2] = i2;
    }
    __syncthreads();
  } else if (w < 2048) {
    // ---- fused=concat(H4,H8,H12) [2048,1536] f32 -> bf16 SWIZZLED ----
    const int qd = (w - 512) * 256 + tid;
    const int L = qd & 63, t2 = qd >> 6;
    const int kc = t2 % 48, mg = t2 / 48;
    const int m = mg * 16 + (L & 15);
    const int k = kc * 32 + (L >> 4) * 8;
    const float* src = (k < 512) ? a.H4 : (k < 1024 ? a.H8 : a.H12);
    const float* sp = &src[(size_t)m * 512 + (k & 511)];
    float4 va = *(const float4*)sp, vb = *(const float4*)(sp + 4);
    ushort8v o;
    o[0] = f32_to_bf16(va.x); o[1] = f32_to_bf16(va.y);
    o[2] = f32_to_bf16(va.z); o[3] = f32_to_bf16(va.w);
    o[4] = f32_to_bf16(vb.x); o[5] = f32_to_bf16(vb.y);
    o[6] = f32_to_bf16(vb.z); o[7] = f32_to_bf16(vb.w);
    *(ushort8v*)&a.fswz[((size_t)(mg * 48 + kc)) * 512 + L * 8] = o;
  } else if (w < 2432) {
    // ---- w1 [512,1536] -> bf16 SWIZZLED ----
    const int qd = (w - 2048) * 256 + tid;
    const int L = qd & 63, t2 = qd >> 6;
    const int kc = t2 % 48, ng = t2 / 48;
    const int n = ng * 16 + (L & 15);
    const int k = kc * 32 + (L >> 4) * 8;
    const float* sp = &a.w1[(size_t)n * 1536 + k];
    float4 va = *(const float4*)sp, vb = *(const float4*)(sp + 4);
    ushort8v o;
    o[0] = f32_to_bf16(va.x); o[1] = f32_to_bf16(va.y);
    o[2] = f32_to_bf16(va.z); o[3] = f32_to_bf16(va.w);
    o[4] = f32_to_bf16(vb.x); o[5] = f32_to_bf16(vb.y);
    o[6] = f32_to_bf16(vb.z); o[7] = f32_to_bf16(vb.w);
    *(ushort8v*)&a.w1s[((size_t)(ng * 48 + kc)) * 512 + L * 8] = o;
  } else if (w < 2560) {
    // ---- w2 [512,512] -> bf16 SWIZZLED ----
    const int qd = (w - 2432) * 256 + tid;
    const int L = qd & 63, t2 = qd >> 6;
    const int kc = t2 & 15, ng = t2 >> 4;
    const int n = ng * 16 + (L & 15);
    const int k = kc * 32 + (L >> 4) * 8;
    const float* sp = &a.w2[(size_t)n * 512 + k];
    float4 va = *(const float4*)sp, vb = *(const float4*)(sp + 4);
    ushort8v o;
    o[0] = f32_to_bf16(va.x); o[1] = f32_to_bf16(va.y);
    o[2] = f32_to_bf16(va.z); o[3] = f32_to_bf16(va.w);
    o[4] = f32_to_bf16(vb.x); o[5] = f32_to_bf16(vb.y);
    o[6] = f32_to_bf16(vb.z); o[7] = f32_to_bf16(vb.w);
    *(ushort8v*)&a.w2s[((size_t)(ng * 16 + kc)) * 512 + L * 8] = o;
  } else {
    // ---- BN constant folding ----
    for (int i = tid; i < 512; i += 256) {
      float sa = a.g1[i] / sqrtf(a.v1[i] + 1e-5f);
      a.s1[i] = sa; a.t1[i] = a.be1[i] - a.m1[i] * sa;
      float sb = a.g2[i] / sqrtf(a.v2[i] + 1e-5f);
      a.s2[i] = sb; a.t2[i] = a.be2[i] - a.m2[i] * sb;
    }
  }
}

// ============ Phase 2: GEMM1  Amatb = bf16(s1*(fused.w1^T + b1) + t1) =======
// 512 blocks, 32x64 tile, barrier-free wave-split-K (4 waves x K=384).
__device__ void phase_gemm1(const FusedArgs& a, char* smem) {
  float* red = (float*)smem;               // [32*65]
  const int tid = threadIdx.x, lane = tid & 63, wv = tid >> 6;
  const int blk = blockIdx.x;
  const int m0 = (blk >> 3) * 32;
  const int n0 = (blk & 7) * 64;
  const unsigned short* Ap = a.fswz + ((size_t)(m0 >> 4) * 48 + wv * 12) * 512 + lane * 8;
  const unsigned short* Bp = a.w1s  + ((size_t)(n0 >> 4) * 48 + wv * 12) * 512 + lane * 8;

  f32x4 acc[2][4];
#pragma unroll
  for (int i = 0; i < 2; ++i)
#pragma unroll
    for (int j = 0; j < 4; ++j) acc[i][j] = (f32x4){0.f, 0.f, 0.f, 0.f};

  bf16x8 af[2], bfr[4], afn[2], bfn[4];
#pragma unroll
  for (int i = 0; i < 2; ++i)
    af[i]  = __builtin_bit_cast(bf16x8, *(const ushort8v*)(Ap + (size_t)i * 48 * 512));
#pragma unroll
  for (int i = 0; i < 4; ++i)
    bfr[i] = __builtin_bit_cast(bf16x8, *(const ushort8v*)(Bp + (size_t)i * 48 * 512));
#pragma unroll 1
  for (int kc = 0; kc < 12; ++kc) {
    if (kc < 11) {
#pragma unroll
      for (int i = 0; i < 2; ++i)
        afn[i] = __builtin_bit_cast(bf16x8, *(const ushort8v*)(Ap + (size_t)i * 48 * 512 + (kc + 1) * 512));
#pragma unroll
      for (int i = 0; i < 4; ++i)
        bfn[i] = __builtin_bit_cast(bf16x8, *(const ushort8v*)(Bp + (size_t)i * 48 * 512 + (kc + 1) * 512));
    }
#pragma unroll
    for (int mi = 0; mi < 2; ++mi)
#pragma unroll
      for (int ni = 0; ni < 4; ++ni)
        acc[mi][ni] = __builtin_amdgcn_mfma_f32_16x16x32_bf16(af[mi], bfr[ni], acc[mi][ni], 0, 0, 0);
#pragma unroll
    for (int i = 0; i < 2; ++i) af[i] = afn[i];
#pragma unroll
    for (int i = 0; i < 4; ++i) bfr[i] = bfn[i];
  }

  // 4-way cross-wave reduce through LDS
  for (int w = 0; w < 4; ++w) {
    if (wv == w) {
#pragma unroll
      for (int mi = 0; mi < 2; ++mi)
#pragma unroll
        for (int ni = 0; ni < 4; ++ni) {
          int col = ni * 16 + (lane & 15);
#pragma unroll
          for (int r = 0; r < 4; ++r) {
            int row = mi * 16 + (lane >> 4) * 4 + r;
            if (w == 0) red[row * 65 + col] = acc[mi][ni][r];
            else        red[row * 65 + col] += acc[mi][ni][r];
          }
        }
    }
    __syncthreads();
  }
  // epilogue: affine -> bf16 (relu deferred to interp), 16B stores
  const int row = tid >> 3;               // 0..31
  const int col = (tid & 7) * 8;          // 0..56
  ushort8v o;
#pragma unroll
  for (int j = 0; j < 8; ++j) {
    int n = n0 + col + j;
    float v = red[row * 65 + col + j];
    o[j] = f32_to_bf16(a.s1[n] * (v + a.b1[n]) + a.t1[n]);
  }
  *(ushort8v*)&a.Amatb[(size_t)(m0 + row) * 512 + n0 + col] = o;
  __syncthreads();
}

// ============ Phase 3: MEGA  interp->LDS then GEMM2 -> out ==================
// 512 blocks; block = 64 points x all 512 outputs. XCD swizzle: each XCD owns
// a contiguous 4096-point range -> its Amatb batch slice (512KB) L2-resident.
// Stage 1: wave per 16-point rowgroup, gathers Amatb (L2) -> 64KB LDS tile in
// fragment order (lane*16B contiguous: conflict-free write & ds_read_b128).
// Stage 2: wave per 128-n slice, acc 4x8, K=512; B from L2-resident w2s.
__device__ void phase_mega(const FusedArgs& a, char* smem) {
  unsigned short* hl = (unsigned short*)smem;   // [64*512] bf16, fragment order
  const int tid = threadIdx.x, lane = tid & 63, wv = tid >> 6;
  const int xcd = blockIdx.x & 7, slot = blockIdx.x >> 3;
  const int m0 = (xcd * 64 + slot) * 64;

  // ---- stage 1: interp 64x512 into LDS ----
  {
    const int p = m0 + wv * 16 + (lane & 15);
    const int b = p >> 13;
    const int i0 = a.nidx[p * 3 + 0], i1 = a.nidx[p * 3 + 1], i2 = a.nidx[p * 3 + 2];
    const float w0 = a.nw[p * 3 + 0], w1v = a.nw[p * 3 + 1], w2v = a.nw[p * 3 + 2];
    const int co = (lane >> 4) * 8;
    const unsigned short* A0 = a.Amatb + ((size_t)(b * 512 + i0)) * 512 + co;
    const unsigned short* A1 = a.Amatb + ((size_t)(b * 512 + i1)) * 512 + co;
    const unsigned short* A2 = a.Amatb + ((size_t)(b * 512 + i2)) * 512 + co;
    unsigned short* wp = hl + (size_t)(wv * 16) * 512 + lane * 8;
#pragma unroll 4
    for (int kc = 0; kc < 16; ++kc) {
      ushort8v u0 = *(const ushort8v*)(A0 + kc * 32);
      ushort8v u1 = *(const ushort8v*)(A1 + kc * 32);
      ushort8v u2 = *(const ushort8v*)(A2 + kc * 32);
      ushort8v o;
#pragma unroll
      for (int j = 0; j < 8; ++j) {
        float v = w0 * bf2f(u0[j]) + w1v * bf2f(u1[j]) + w2v * bf2f(u2[j]);
        o[j] = f32_to_bf16(fmaxf(v, 0.f));
      }
      *(ushort8v*)(wp + (size_t)kc * 512) = o;
    }
  }
  __syncthreads();

  // ---- stage 2: out[m0..m0+63][:] = relu(s2*(hl . w2s^T + b2) + t2) ----
  const int n0 = wv * 128;
  const unsigned short* Bbase = a.w2s + (size_t)(n0 >> 4) * 16 * 512 + lane * 8;

  f32x4 acc[4][8];
#pragma unroll
  for (int i = 0; i < 4; ++i)
#pragma unroll
    for (int j = 0; j < 8; ++j) acc[i][j] = (f32x4){0.f, 0.f, 0.f, 0.f};

#pragma unroll 1
  for (int kc = 0; kc < 16; ++kc) {
    bf16x8 af[4], bfr[8];
#pragma unroll
    for (int mi = 0; mi < 4; ++mi)
      af[mi] = __builtin_bit_cast(bf16x8,
          *(const ushort8v*)(hl + (size_t)(mi * 16 + kc) * 512 + lane * 8));
#pragma unroll
    for (int ni = 0; ni < 8; ++ni)
      bfr[ni] = __builtin_bit_cast(bf16x8,
          *(const ushort8v*)(Bbase + (size_t)(ni * 16 + kc) * 512));
#pragma unroll
    for (int mi = 0; mi < 4; ++mi)
#pragma unroll
      for (int ni = 0; ni < 8; ++ni)
        acc[mi][ni] = __builtin_amdgcn_mfma_f32_16x16x32_bf16(af[mi], bfr[ni], acc[mi][ni], 0, 0, 0);
  }

  // C/D layout: n = lane&15, m = (lane>>4)*4 + reg   [m89-verified]
#pragma unroll
  for (int mi = 0; mi < 4; ++mi) {
    int mbase = m0 + mi * 16 + (lane >> 4) * 4;
#pragma unroll
    for (int ni = 0; ni < 8; ++ni) {
      int n = n0 + ni * 16 + (lane & 15);
      float s = a.s2[n], bb = a.b2[n], t = a.t2[n];
      f32x4 v = acc[mi][ni];
#pragma unroll
      for (int r = 0; r < 4; ++r)
        a.outp[(size_t)(mbase + r) * 512 + n] = fmaxf(s * (v[r] + bb) + t, 0.f);
    }
  }
}

// ============ cooperative fused kernel: 512 blocks, 2 blocks/CU =============
__global__ __launch_bounds__(256, 2) void fused_kernel(FusedArgs a) {
  __shared__ __align__(16) char smem[65536];
  cg::grid_group grid = cg::this_grid();
  const int blk = blockIdx.x;
  for (int u = blk; u <= 2560; u += 512) phase_setup(a, smem, u);
  grid.sync();
  phase_gemm1(a, smem);
  grid.sync();
  phase_mega(a, smem);
}

// ============ fallback standalone kernels (same device code) ================
__global__ __launch_bounds__(256) void k_setup(FusedArgs a) {
  __shared__ __align__(16) char smem[8448];
  for (int u = blockIdx.x; u <= 2560; u += 512) phase_setup(a, smem, u);
}
__global__ __launch_bounds__(256) void k_gemm1(FusedArgs a) {
  __shared__ __align__(16) char smem[8448];
  phase_gemm1(a, smem);
}
__global__ __launch_bounds__(256, 2) void k_mega(FusedArgs a) {
  __shared__ __align__(16) char smem[65536];
  phase_mega(a, smem);
}

extern "C" void kernel_launch(void* const* d_in, const int* in_sizes, int n_in,
                              void* d_out, int out_size, void* d_ws, size_t ws_size,
                              hipStream_t stream) {
  char* ws = (char*)d_ws;
  FusedArgs a;
  a.xyz     = (const float*)d_in[0];
  a.centers = (const float*)d_in[1];
  a.H4      = (const float*)d_in[2];
  a.H8      = (const float*)d_in[3];
  a.H12     = (const float*)d_in[4];
  a.w1      = (const float*)d_in[5];
  a.b1      = (const float*)d_in[6];
  a.g1      = (const float*)d_in[7];
  a.be1     = (const float*)d_in[8];
  a.m1      = (const float*)d_in[9];
  a.v1      = (const float*)d_in[10];
  a.w2      = (const float*)d_in[11];
  a.b2      = (const float*)d_in[12];
  a.g2      = (const float*)d_in[13];
  a.be2     = (const float*)d_in[14];
  a.m2      = (const float*)d_in[15];
  a.v2      = (const float*)d_in[16];
  a.fswz  = (unsigned short*)(ws);                // 6,291,456 B
  a.w1s   = (unsigned short*)(ws + 6291456);      // 1,572,864 B
  a.w2s   = (unsigned short*)(ws + 7864320);      //   524,288 B
  a.Amatb = (unsigned short*)(ws + 8388608);      // 2,097,152 B (bf16)
  a.nidx  = (int*)           (ws + 10485760);     //   393,216 B
  a.nw    = (float*)         (ws + 10878976);     //   393,216 B
  a.s1    = (float*)         (ws + 11272192);
  a.t1 = a.s1 + 512; a.s2 = a.t1 + 512; a.t2 = a.s2 + 512;
  a.outp  = (float*)d_out;

  // Occupancy-gated cooperative launch: pure host query (capture-safe).
  int nb = 0;
  hipError_t qerr = hipOccupancyMaxActiveBlocksPerMultiprocessor(
      &nb, reinterpret_cast<const void*>(fused_kernel), 256, 0);
  bool coop_ok = (qerr == hipSuccess) && (nb >= 2);
  if (coop_ok) {
    void* kp[] = { (void*)&a };
    hipError_t lerr = hipLaunchCooperativeKernel(
        (const void*)fused_kernel, dim3(512), dim3(256), kp, 0, stream);
    coop_ok = (lerr == hipSuccess);
  }
  if (!coop_ok) {
    k_setup <<<512, 256, 0, stream>>>(a);
    k_gemm1 <<<512, 256, 0, stream>>>(a);
    k_mega  <<<512, 256, 0, stream>>>(a);
  }
}